// Round 1
// baseline (627.297 us; speedup 1.0000x reference)
//
#include <hip/hip_runtime.h>
#include <hip/hip_bf16.h>

// ResGraphModule on MI355X (gfx950), fp32.
//   e   = edge_attr @ W_edge                  [E,64]@[64,256]
//   agg = segment_sum(x[src] * e, dst)        [N,256]
//   h   = relu(agg@W_rel + b_rel + x@W_root)  [N,256]
//   h   = BN_train(h) * gamma + beta
//   out = h + x@W_res
//
// Structure: bucket edges by dst (dense [N][64] list, no fp32 atomics) ->
// node-major aggregation with W_edge in VGPRs + scalar edge_attr loads ->
// fused triple GEMM + ReLU + BN partial sums -> elementwise BN finalize.

#define N_NODES 20000
#define E_EDGES 320000
#define C 256      // IN == OUT
#define CE 64      // edge channels
#define MAXDEG 64
#define BN_EPS 1e-5f
#define NT 16      // node tile for gemm kernel (20000 % 16 == 0)

// ---------------------------------------------------------------- kernel A
// Bucket edges by destination node. deg[] must be pre-zeroed.
__global__ void k_bucket(const int* __restrict__ ei, int* __restrict__ deg,
                         int* __restrict__ elist) {
    int e = blockIdx.x * blockDim.x + threadIdx.x;
    if (e < E_EDGES) {
        int d = ei[E_EDGES + e];               // dst = edge_index[1][e]
        int slot = atomicAdd(&deg[d], 1);
        if (slot < MAXDEG) elist[d * MAXDEG + slot] = e;
    }
}

// ---------------------------------------------------------------- kernel B
// Node-major aggregation. Thread = output channel c (256 threads/block).
// W_edge column c lives in 64 VGPRs. Per edge: edge_attr row is wave-uniform
// -> scalar loads; inner loop is 64 v_fmac_f32 (SGPR x VGPR), no LDS.
__global__ __launch_bounds__(256) void k_aggregate(
    const float* __restrict__ x, const int* __restrict__ ei,
    const float* __restrict__ ea, const float* __restrict__ W_edge,
    const int* __restrict__ deg, const int* __restrict__ elist,
    float* __restrict__ agg) {
    const int c = threadIdx.x;
    float w[CE];
#pragma unroll
    for (int k = 0; k < CE; ++k) w[k] = W_edge[k * C + c];

    for (int node = blockIdx.x; node < N_NODES; node += gridDim.x) {
        int d = deg[node];
        d = __builtin_amdgcn_readfirstlane(d < MAXDEG ? d : MAXDEG);
        const int* lst = elist + node * MAXDEG;
        float acc = 0.f;
        for (int i = 0; i < d; ++i) {
            int e = __builtin_amdgcn_readfirstlane(lst[i]);
            int s = __builtin_amdgcn_readfirstlane(ei[e]);   // src node
            const float* eap = ea + (size_t)e * CE;          // uniform row
            float xv = x[(size_t)s * C + c];                 // coalesced 256B
            float e0 = 0.f, e1 = 0.f, e2 = 0.f, e3 = 0.f;
#pragma unroll
            for (int k = 0; k < CE; k += 4) {
                e0 += eap[k + 0] * w[k + 0];
                e1 += eap[k + 1] * w[k + 1];
                e2 += eap[k + 2] * w[k + 2];
                e3 += eap[k + 3] * w[k + 3];
            }
            acc += xv * ((e0 + e1) + (e2 + e3));
        }
        agg[(size_t)node * C + c] = acc;
    }
}

// ---------------------------------------------------------------- kernel C
// Fused: t = relu(agg@W_rel + b_rel + x@W_root); r = x@W_res;
// BN partial sums (sum, sumsq per channel) via 2 atomics/channel/block.
// t overwrites the agg region (tile fully staged to LDS before any store).
__global__ __launch_bounds__(256) void k_gemm_bn(
    const float* __restrict__ x, const float* __restrict__ W_rel,
    const float* __restrict__ b_rel, const float* __restrict__ W_root,
    const float* __restrict__ W_res, float* aggt, float* __restrict__ r,
    float* __restrict__ chsum, float* __restrict__ chsumsq) {
    __shared__ float a_lds[NT][C];
    __shared__ float x_lds[NT][C];
    const int c = threadIdx.x;
    const int n0 = blockIdx.x * NT;

#pragma unroll
    for (int n = 0; n < NT; ++n) {
        a_lds[n][c] = aggt[(size_t)(n0 + n) * C + c];
        x_lds[n][c] = x[(size_t)(n0 + n) * C + c];
    }
    __syncthreads();

    float acc_rel[NT], acc_root[NT], acc_res[NT];
#pragma unroll
    for (int n = 0; n < NT; ++n) acc_rel[n] = acc_root[n] = acc_res[n] = 0.f;

    for (int k = 0; k < C; k += 4) {
        float wl0 = W_rel[(k + 0) * C + c], wl1 = W_rel[(k + 1) * C + c];
        float wl2 = W_rel[(k + 2) * C + c], wl3 = W_rel[(k + 3) * C + c];
        float wo0 = W_root[(k + 0) * C + c], wo1 = W_root[(k + 1) * C + c];
        float wo2 = W_root[(k + 2) * C + c], wo3 = W_root[(k + 3) * C + c];
        float wr0 = W_res[(k + 0) * C + c], wr1 = W_res[(k + 1) * C + c];
        float wr2 = W_res[(k + 2) * C + c], wr3 = W_res[(k + 3) * C + c];
#pragma unroll
        for (int n = 0; n < NT; ++n) {
            float4 av = *reinterpret_cast<const float4*>(&a_lds[n][k]);
            float4 xv = *reinterpret_cast<const float4*>(&x_lds[n][k]);
            acc_rel[n]  += av.x * wl0 + av.y * wl1 + av.z * wl2 + av.w * wl3;
            acc_root[n] += xv.x * wo0 + xv.y * wo1 + xv.z * wo2 + xv.w * wo3;
            acc_res[n]  += xv.x * wr0 + xv.y * wr1 + xv.z * wr2 + xv.w * wr3;
        }
    }

    const float bias = b_rel[c];
    float s1 = 0.f, s2 = 0.f;
#pragma unroll
    for (int n = 0; n < NT; ++n) {
        float h = acc_rel[n] + bias + acc_root[n];
        h = fmaxf(h, 0.f);
        s1 += h;
        s2 += h * h;
        aggt[(size_t)(n0 + n) * C + c] = h;          // t overwrites agg
        r[(size_t)(n0 + n) * C + c] = acc_res[n];
    }
    atomicAdd(&chsum[c], s1);
    atomicAdd(&chsumsq[c], s2);
}

// ---------------------------------------------------------------- kernel D
// out = (t - mean) * rsqrt(var + eps) * gamma + beta + r
__global__ __launch_bounds__(256) void k_finalize(
    const float* __restrict__ t, const float* __restrict__ r,
    const float* __restrict__ chsum, const float* __restrict__ chsumsq,
    const float* __restrict__ gamma, const float* __restrict__ beta,
    float* __restrict__ out) {
    const float invN = 1.f / (float)N_NODES;
    int i = (blockIdx.x * blockDim.x + threadIdx.x) * 4;
    if (i >= N_NODES * C) return;
    int c = i & (C - 1);    // rows are 256 wide, i%4==0 -> c..c+3 in-row
    float4 tv = *reinterpret_cast<const float4*>(&t[i]);
    float4 rv = *reinterpret_cast<const float4*>(&r[i]);
    float4 o;
    {
        float m = chsum[c + 0] * invN;
        float v = chsumsq[c + 0] * invN - m * m;
        o.x = (tv.x - m) * rsqrtf(v + BN_EPS) * gamma[c + 0] + beta[c + 0] + rv.x;
    }
    {
        float m = chsum[c + 1] * invN;
        float v = chsumsq[c + 1] * invN - m * m;
        o.y = (tv.y - m) * rsqrtf(v + BN_EPS) * gamma[c + 1] + beta[c + 1] + rv.y;
    }
    {
        float m = chsum[c + 2] * invN;
        float v = chsumsq[c + 2] * invN - m * m;
        o.z = (tv.z - m) * rsqrtf(v + BN_EPS) * gamma[c + 2] + beta[c + 2] + rv.z;
    }
    {
        float m = chsum[c + 3] * invN;
        float v = chsumsq[c + 3] * invN - m * m;
        o.w = (tv.w - m) * rsqrtf(v + BN_EPS) * gamma[c + 3] + beta[c + 3] + rv.w;
    }
    *reinterpret_cast<float4*>(&out[i]) = o;
}

// ---------------------------------------------------------------- launch
extern "C" void kernel_launch(void* const* d_in, const int* in_sizes, int n_in,
                              void* d_out, int out_size, void* d_ws, size_t ws_size,
                              hipStream_t stream) {
    const float* x      = (const float*)d_in[0];
    const int*   ei     = (const int*)  d_in[1];
    const float* ea     = (const float*)d_in[2];
    const float* W_edge = (const float*)d_in[3];
    const float* W_rel  = (const float*)d_in[4];
    const float* b_rel  = (const float*)d_in[5];
    const float* W_root = (const float*)d_in[6];
    const float* gamma  = (const float*)d_in[7];
    const float* beta   = (const float*)d_in[8];
    const float* W_res  = (const float*)d_in[9];
    float* out = (float*)d_out;

    // ws layout (floats/ints, 4B units):
    //   [0)              aggt : N*C   (agg, later overwritten by t)
    //   [N*C)            r    : N*C
    //   [2*N*C)          chsum: 256, chsumsq: 256
    //   then             deg  : N ints, elist : N*MAXDEG ints
    float* ws      = (float*)d_ws;
    float* aggt    = ws;
    float* r       = ws + (size_t)N_NODES * C;
    float* chsum   = ws + 2 * (size_t)N_NODES * C;
    float* chsumsq = chsum + C;
    int*   deg     = (int*)(chsumsq + C);
    int*   elist   = deg + N_NODES;

    // zero chsum+chsumsq+deg in one shot (ws is poisoned 0xAA before launch)
    hipMemsetAsync(chsum, 0, (2 * C + N_NODES) * sizeof(int), stream);

    k_bucket<<<(E_EDGES + 255) / 256, 256, 0, stream>>>(ei, deg, elist);
    k_aggregate<<<2500, 256, 0, stream>>>(x, ei, ea, W_edge, deg, elist, aggt);
    k_gemm_bn<<<N_NODES / NT, 256, 0, stream>>>(x, W_rel, b_rel, W_root, W_res,
                                                aggt, r, chsum, chsumsq);
    k_finalize<<<(N_NODES * C / 4 + 255) / 256, 256, 0, stream>>>(
        aggt, r, chsum, chsumsq, gamma, beta, out);
}